// Round 9
// baseline (238.948 us; speedup 1.0000x reference)
//
#include <hip/hip_runtime.h>

// Problem constants
#define B_DIM 32
#define V_DIM 21
#define D_DIM 512
#define P_DIM 64
#define M_TOTAL 672          // B*V
#define K_TOTAL 32768        // D*P
#define OUT_DIM 96
#define E_DIM 8
#define R_DIM 8
#define H_DIM 256
#define N_TOTAL 160          // OUT_DIM + E*R
#define SCALING 2.0f
#define POOL_SCALE (1.0f / (V_DIM * (float)P_DIM))

// GEMM: barrier-free, all-NAMED-register pipeline; pooling deferred to
// registers (v9's single change vs v8: no per-chunk shfl/atomic chain).
#define BM 64
#define BK 32
#define KSPLIT 64
#define K_PER_SPLIT (K_TOTAL / KSPLIT)   // 512
#define CHUNKS (K_PER_SPLIT / BK)        // 16
#define SMN (M_TOTAL * N_TOTAL)          // 107520 per partial plane
#define NMB 11                           // m-blocks
#define RC_ROWS 6                        // rows per reduce_combine block (672/6=112)

typedef __attribute__((ext_vector_type(4))) float floatx4;
typedef __attribute__((ext_vector_type(8))) short short8;

__device__ __forceinline__ unsigned short f2bf(float f) {
  union { float f; unsigned int u; } v; v.f = f;
  unsigned int u = v.u + (0x7FFFu + ((v.u >> 16) & 1u));  // RNE
  return (unsigned short)(u >> 16);
}

// v_cvt_pk_bf16_f32: RNE, lo -> bits[15:0], hi -> bits[31:16] (matches f2bf)
__device__ __forceinline__ unsigned int cvt_pk_bf16(float lo, float hi) {
  unsigned int r;
  asm("v_cvt_pk_bf16_f32 %0, %1, %2" : "=v"(r) : "v"(lo), "v"(hi));
  return r;
}

// ------- convW: [W_base|lora_A] fp32 -> bf16 Wb, FRAGMENT-MAJOR:
// off = ((ky*16 + c)*10 + nt)*512 + l16*32 + quad*8  (ky=k>>9, c=(k>>5)&15,
// quad=(k>>3)&3, row=nt*16+l16). Each gemm B-fragment read (64 lanes over
// l16 x quad) is 1KB contiguous -> fully coalesced, L1/L2-friendly.
__global__ __launch_bounds__(256)
void convW_kernel(const float* __restrict__ W_base, const float* __restrict__ lora_A,
                  short* __restrict__ Wb) {
  int gid = blockIdx.x * 256 + threadIdx.x;
  size_t base = (size_t)gid * 8;          // element index (8-aligned)
  int row = (int)(base >> 15);
  int k = (int)(base & 32767);
  const float* src = (row < OUT_DIM) ? (W_base + ((size_t)row << 15) + k)
                                     : (lora_A + ((size_t)(row - OUT_DIM) << 15) + k);
  floatx4 v0 = ((const floatx4*)src)[0];
  floatx4 v1 = ((const floatx4*)src)[1];
  short8 sv;
  sv[0] = (short)f2bf(v0[0]); sv[1] = (short)f2bf(v0[1]);
  sv[2] = (short)f2bf(v0[2]); sv[3] = (short)f2bf(v0[3]);
  sv[4] = (short)f2bf(v1[0]); sv[5] = (short)f2bf(v1[1]);
  sv[6] = (short)f2bf(v1[2]); sv[7] = (short)f2bf(v1[3]);
  int ky = k >> 9, c = (k >> 5) & 15, quad = (k >> 3) & 3;
  int nt = row >> 4, l16 = row & 15;
  size_t off = ((size_t)(ky * 16 + c) * 10 + nt) * 512 + l16 * 32 + quad * 8;
  *(short8*)(Wb + off) = sv;
}

// ------- gemm v9: == v8 (16 hand-expanded K-steps, named regs, no in-loop
// barriers/waitcnt) with ONE change: pooling accumulates into 8 per-lane
// scalar registers (pure VALU, no cross-lane ops in the loop); the
// shfl(ds_bpermute)+LDS-atomic flush runs ONCE at kernel end instead of
// per chunk. A/B test of the "per-chunk cross-lane chain" theory.
__global__ __launch_bounds__(256, 3)
void gemm_kernel(const float* __restrict__ x, const short* __restrict__ Wb,
                 float* __restrict__ P, float* __restrict__ pp) {
  __shared__ float lds_pool[5 * 8];       // [b_local][d_local]

  const int tid = threadIdx.x;
  const int bid = blockIdx.x;
  const int xcd = bid & 7;
  const int grp = bid >> 3;               // 0..87
  const int ky  = xcd + 8 * (grp / NMB);  // 0..63
  const int mb  = grp % NMB;              // 0..10
  const int m0 = mb * BM;
  const int kbase = ky * K_PER_SPLIT;
  const int lane = tid & 63;
  const int wave = tid >> 6;              // 0..3
  const int quad = lane >> 4;
  const int l16 = lane & 15;
  const int b_first = m0 / V_DIM;

  if (tid < 40) lds_pool[tid] = 0.0f;
  __syncthreads();                        // publish pool zeros

  // A: lane (l16,quad) owns row m0+wave*16+l16, k-window quad*8 within chunk.
  const int arow_raw = m0 + wave * 16 + l16;
  const bool row_ok = (arow_raw < M_TOTAL);
  const int arow = row_ok ? arow_raw : (M_TOTAL - 1);
  const floatx4* aptr =
      (const floatx4*)(x + (size_t)arow * K_TOTAL + kbase + quad * 8);
  // B fragment base: chunk c, tile nt at bbase + c*5120 + nt*512 (shorts)
  const short* bbase = Wb + (size_t)ky * (CHUNKS * 5120) + l16 * 32 + quad * 8;
  const int pool_idx = (arow / V_DIM - b_first) * 8;

  floatx4 acc0 = (floatx4)(0.0f), acc1 = (floatx4)(0.0f), acc2 = (floatx4)(0.0f),
          acc3 = (floatx4)(0.0f), acc4 = (floatx4)(0.0f), acc5 = (floatx4)(0.0f),
          acc6 = (floatx4)(0.0f), acc7 = (floatx4)(0.0f), acc8 = (floatx4)(0.0f),
          acc9 = (floatx4)(0.0f);
  // per-lane pooling accumulators, one per d (chunk-pair)
  float pc0 = 0.0f, pc1 = 0.0f, pc2 = 0.0f, pc3 = 0.0f,
        pc4 = 0.0f, pc5 = 0.0f, pc6 = 0.0f, pc7 = 0.0f;

  // A pipeline prologue: chunks 0..3 in named regs (depth 4)
  floatx4 af00 = aptr[0],  af01 = aptr[1];
  floatx4 af10 = aptr[8],  af11 = aptr[9];
  floatx4 af20 = aptr[16], af21 = aptr[17];
  floatx4 af30 = aptr[24], af31 = aptr[25];

#define MFMA(d, a, b) d = __builtin_amdgcn_mfma_f32_16x16x32_bf16(a, b, d, 0, 0, 0)

#define GSTEP(c, AB, PD)                                                      \
  {                                                                           \
    const short8* bc = (const short8*)(bbase + (c) * 5120);                   \
    short8 b0 = bc[0],   b1 = bc[64],  b2 = bc[128], b3 = bc[192],            \
           b4 = bc[256], b5 = bc[320], b6 = bc[384], b7 = bc[448],            \
           b8 = bc[512], b9 = bc[576];                                        \
    floatx4 f0 = af##AB##0, f1 = af##AB##1;                                   \
    if ((c) + 4 < CHUNKS) {                                                   \
      af##AB##0 = aptr[((c) + 4) * 8];                                        \
      af##AB##1 = aptr[((c) + 4) * 8 + 1];                                    \
    }                                                                         \
    union { short8 s; unsigned int u[4]; } av;                                \
    av.u[0] = cvt_pk_bf16(f0[0], f0[1]);                                      \
    av.u[1] = cvt_pk_bf16(f0[2], f0[3]);                                      \
    av.u[2] = cvt_pk_bf16(f1[0], f1[1]);                                      \
    av.u[3] = cvt_pk_bf16(f1[2], f1[3]);                                      \
    PD += ((f0[0] + f0[1]) + (f0[2] + f0[3])) +                               \
          ((f1[0] + f1[1]) + (f1[2] + f1[3]));                                \
    MFMA(acc0, av.s, b0); MFMA(acc1, av.s, b1); MFMA(acc2, av.s, b2);         \
    MFMA(acc3, av.s, b3); MFMA(acc4, av.s, b4); MFMA(acc5, av.s, b5);         \
    MFMA(acc6, av.s, b6); MFMA(acc7, av.s, b7); MFMA(acc8, av.s, b8);         \
    MFMA(acc9, av.s, b9);                                                     \
  }

  GSTEP(0, 0, pc0)  GSTEP(1, 1, pc0)  GSTEP(2, 2, pc1)  GSTEP(3, 3, pc1)
  GSTEP(4, 0, pc2)  GSTEP(5, 1, pc2)  GSTEP(6, 2, pc3)  GSTEP(7, 3, pc3)
  GSTEP(8, 0, pc4)  GSTEP(9, 1, pc4)  GSTEP(10, 2, pc5) GSTEP(11, 3, pc5)
  GSTEP(12, 0, pc6) GSTEP(13, 1, pc6) GSTEP(14, 2, pc7) GSTEP(15, 3, pc7)
#undef GSTEP
#undef MFMA

  // deferred pooling flush: 8 independent shfl chains, once per kernel.
  // lanes l16, l16+16, l16+32, l16+48 share a row; lane<16 holds the row sum.
#define PFLUSH(d, PD)                                                         \
  {                                                                           \
    float h = PD;                                                             \
    h += __shfl_down(h, 32);                                                  \
    h += __shfl_down(h, 16);                                                  \
    if (lane < 16 && row_ok) atomicAdd(&lds_pool[pool_idx + (d)], h);         \
  }
  PFLUSH(0, pc0) PFLUSH(1, pc1) PFLUSH(2, pc2) PFLUSH(3, pc3)
  PFLUSH(4, pc4) PFLUSH(5, pc5) PFLUSH(6, pc6) PFLUSH(7, pc7)
#undef PFLUSH

  __syncthreads();                        // pool atomics visible

  // partial-plane store (D layout: col=lane&15, row=quad*4+reg)
  {
    const int mrow = m0 + wave * 16 + quad * 4;
    float* Pp = P + (size_t)ky * SMN + (size_t)mrow * N_TOTAL + l16;
    floatx4 accs[10] = {acc0, acc1, acc2, acc3, acc4, acc5, acc6, acc7, acc8, acc9};
    #pragma unroll
    for (int r = 0; r < 4; ++r)
      if (mrow + r < M_TOTAL)
        #pragma unroll
        for (int nt = 0; nt < 10; ++nt)
          Pp[(size_t)r * N_TOTAL + nt * 16] = accs[nt][r];
  }

  // pooled partials: unique owner (mb, bl, ky, d) -> plain store, no atomics
  if (tid < 40) {
    int bl = tid >> 3, dl = tid & 7;
    pp[((size_t)(mb * 5 + bl)) * D_DIM + ky * 8 + dl] = lds_pool[tid];
  }
}

// ---------------- router: gather pooled from pp, MLP + softmax + top-2 ------
__global__ __launch_bounds__(256)
void router_kernel(const float* __restrict__ pp, const float* __restrict__ W1,
                   const float* __restrict__ b1, const float* __restrict__ W2,
                   const float* __restrict__ b2, float* __restrict__ wfull,
                   float* __restrict__ probs_out) {
  __shared__ float sp[D_DIM];
  __shared__ float sh[H_DIM];
  __shared__ float slog[E_DIM];
  const int b = blockIdx.x;
  const int t = threadIdx.x;
  // rows of batch b live in m-blocks mb1..mb2 (at most 2)
  const int mb1 = (b * V_DIM) / BM;
  const int mb2 = (b * V_DIM + V_DIM - 1) / BM;
  const int bf1 = (mb1 * BM) / V_DIM;
  const int bf2 = (mb2 * BM) / V_DIM;
  const float* p1 = pp + (size_t)(mb1 * 5 + (b - bf1)) * D_DIM;
  const float* p2 = pp + (size_t)(mb2 * 5 + (b - bf2)) * D_DIM;
  for (int d = t; d < D_DIM; d += 256) {
    float v = p1[d];
    if (mb2 != mb1) v += p2[d];
    sp[d] = v * POOL_SCALE;
  }
  __syncthreads();
  float acc = b1[t];
  const float* w1r = W1 + (size_t)t * D_DIM;
  for (int d = 0; d < D_DIM; ++d) acc += sp[d] * w1r[d];
  sh[t] = fmaxf(acc, 0.0f);
  __syncthreads();
  if (t < E_DIM) {
    float a = b2[t];
    const float* w2r = W2 + t * H_DIM;
    for (int j = 0; j < H_DIM; ++j) a += sh[j] * w2r[j];
    slog[t] = a;
  }
  __syncthreads();
  if (t == 0) {
    float p[E_DIM];
    float mx = slog[0];
    for (int e = 1; e < E_DIM; ++e) mx = fmaxf(mx, slog[e]);
    float se = 0.0f;
    for (int e = 0; e < E_DIM; ++e) { p[e] = __expf(slog[e] - mx); se += p[e]; }
    float inv = 1.0f / se;
    for (int e = 0; e < E_DIM; ++e) { p[e] *= inv; probs_out[b * E_DIM + e] = p[e]; }
    // top-2, lowest index wins ties (strict > keeps earlier index)
    int i0 = 0;
    for (int e = 1; e < E_DIM; ++e) if (p[e] > p[i0]) i0 = e;
    int i1 = (i0 == 0) ? 1 : 0;
    for (int e = 0; e < E_DIM; ++e) if (e != i0 && p[e] > p[i1]) i1 = e;
    float s2 = p[i0] + p[i1];
    float invs = 1.0f / fmaxf(s2, 1e-6f);
    for (int e = 0; e < E_DIM; ++e) {
      float w = 0.0f;
      if (e == i0) w += p[i0] * invs;
      if (e == i1) w += p[i1] * invs;
      wfull[b * E_DIM + e] = w;
    }
  }
}

// ------- reduce partials over KSPLIT + combine: out = S_b + b_base + 2*Σ w·(S_l·B)
__global__ __launch_bounds__(256)
void reduce_combine_kernel(const float* __restrict__ P, const float* __restrict__ b_base,
                           const float* __restrict__ lora_B, const float* __restrict__ wfull,
                           float* __restrict__ out) {
  __shared__ float sS[RC_ROWS * N_TOTAL];   // 960 floats
  const int t = threadIdx.x;
  const int NF4 = RC_ROWS * N_TOTAL / 4;    // 240 float4 per block
  if (t < NF4) {
    const floatx4* P4 = (const floatx4*)P;
    size_t base = (size_t)blockIdx.x * NF4 + t;
    floatx4 a = (floatx4)(0.0f);
    #pragma unroll 8
    for (int k = 0; k < KSPLIT; ++k) a += P4[(size_t)k * (SMN / 4) + base];
    *(floatx4*)&sS[t * 4] = a;
  }
  __syncthreads();
  for (int i = t; i < RC_ROWS * OUT_DIM; i += 256) {
    int mr = i / OUT_DIM;
    int o = i - mr * OUT_DIM;
    int mm = blockIdx.x * RC_ROWS + mr;
    int b = mm / V_DIM;
    const float* srow = sS + mr * N_TOTAL;
    float res = srow[o] + b_base[o];
    float moe = 0.0f;
    #pragma unroll
    for (int e = 0; e < E_DIM; ++e) {
      float we = wfull[b * E_DIM + e];
      if (we != 0.0f) {
        const float* lb = lora_B + ((size_t)e * OUT_DIM + o) * R_DIM;
        float dd = 0.0f;
        #pragma unroll
        for (int r = 0; r < R_DIM; ++r) dd += srow[OUT_DIM + e * R_DIM + r] * lb[r];
        moe += we * dd;
      }
    }
    out[(size_t)mm * OUT_DIM + o] = res + SCALING * moe;
  }
}

extern "C" void kernel_launch(void* const* d_in, const int* in_sizes, int n_in,
                              void* d_out, int out_size, void* d_ws, size_t ws_size,
                              hipStream_t stream) {
  const float* x      = (const float*)d_in[0];
  const float* W_base = (const float*)d_in[1];
  const float* b_base = (const float*)d_in[2];
  const float* W1     = (const float*)d_in[3];
  const float* b1     = (const float*)d_in[4];
  const float* W2     = (const float*)d_in[5];
  const float* b2     = (const float*)d_in[6];
  const float* lora_A = (const float*)d_in[7];
  const float* lora_B = (const float*)d_in[8];
  float* out = (float*)d_out;

  // ws layout: pp[11*5*512 f] | wfull[256 f] | Wb[160*32768 bf16] | P[64*107520 f]
  float* ws    = (float*)d_ws;
  float* pp    = ws;
  float* wfull = ws + NMB * 5 * D_DIM;
  short* Wb    = (short*)(wfull + 256);
  float* P     = (float*)(Wb + (size_t)N_TOTAL * K_TOTAL);

  convW_kernel<<<(N_TOTAL * K_TOTAL / 8 + 255) / 256, 256, 0, stream>>>(
      W_base, lora_A, Wb);
  gemm_kernel<<<NMB * KSPLIT, 256, 0, stream>>>(x, Wb, P, pp);
  router_kernel<<<B_DIM, 256, 0, stream>>>(pp, W1, b1, W2, b2, wfull,
                                           out + (size_t)M_TOTAL * OUT_DIM);
  reduce_combine_kernel<<<M_TOTAL / RC_ROWS, 256, 0, stream>>>(
      P, b_base, lora_B, wfull, out);
}

// Round 10
// 205.913 us; speedup vs baseline: 1.1604x; 1.1604x over previous
//
#include <hip/hip_runtime.h>

// Problem constants
#define B_DIM 32
#define V_DIM 21
#define D_DIM 512
#define P_DIM 64
#define M_TOTAL 672          // B*V
#define K_TOTAL 32768        // D*P
#define OUT_DIM 96
#define E_DIM 8
#define R_DIM 8
#define H_DIM 256
#define N_TOTAL 160          // OUT_DIM + E*R
#define SCALING 2.0f
#define POOL_SCALE (1.0f / (V_DIM * (float)P_DIM))

// GEMM tiling: coalesced LDS staging, small tiles for residency.
#define BM 64
#define BK 64
#define KSPLIT 64
#define K_PER_SPLIT (K_TOTAL / KSPLIT)   // 512
#define CHUNKS (K_PER_SPLIT / BK)        // 8
#define LDS_K (BK + 8)                   // 72 shorts/row: row stride 144B -> 4-bank rotate
#define SMN (M_TOTAL * N_TOTAL)          // 107520 per partial plane
#define RC_ROWS 4                        // rows per reduce_combine block

typedef __attribute__((ext_vector_type(4))) float floatx4;
typedef __attribute__((ext_vector_type(8))) short short8;
typedef __attribute__((ext_vector_type(4))) short shortx4;  // 'short4' is a HIP builtin

__device__ __forceinline__ unsigned short f2bf(float f) {
  union { float f; unsigned int u; } v; v.f = f;
  unsigned int u = v.u + (0x7FFFu + ((v.u >> 16) & 1u));  // RNE
  return (unsigned short)(u >> 16);
}

// ------- convW: [W_base|lora_A] fp32 -> bf16 Wb[160][32768]; also zero pooled
__global__ __launch_bounds__(256)
void convW_kernel(const float* __restrict__ W_base, const float* __restrict__ lora_A,
                  short* __restrict__ Wb, float* __restrict__ pooled) {
  int gid = blockIdx.x * 256 + threadIdx.x;
  if (blockIdx.x < 64) pooled[gid] = 0.0f;   // 16384 floats zeroed (grid is 2560 blocks)
  size_t base = (size_t)gid * 8;
  int row = (int)(base >> 15);
  int k = (int)(base & 32767);
  const float* src = (row < OUT_DIM) ? (W_base + ((size_t)row << 15) + k)
                                     : (lora_A + ((size_t)(row - OUT_DIM) << 15) + k);
  floatx4 v0 = ((const floatx4*)src)[0];
  floatx4 v1 = ((const floatx4*)src)[1];
  short8 sv;
  sv[0] = (short)f2bf(v0[0]); sv[1] = (short)f2bf(v0[1]);
  sv[2] = (short)f2bf(v0[2]); sv[3] = (short)f2bf(v0[3]);
  sv[4] = (short)f2bf(v1[0]); sv[5] = (short)f2bf(v1[1]);
  sv[6] = (short)f2bf(v1[2]); sv[7] = (short)f2bf(v1[3]);
  *(short8*)(Wb + base) = sv;
}

// ------- gemm: P[ky][m][n] = x-chunk @ Wb^T; A,B staged via LDS (coalesced);
// plain-store partials; pooling fused via shuffle tree. 4 blocks/CU resident.
__global__ __launch_bounds__(256, 4)
void gemm_kernel(const float* __restrict__ x, const short* __restrict__ Wb,
                 float* __restrict__ P, float* __restrict__ pooled) {
  __shared__ short ldsA[BM * LDS_K];      //  9,216 B
  __shared__ short ldsB[N_TOTAL * LDS_K]; // 23,040 B
  __shared__ float lds_pool[5 * 8];       // [b_local][d_local = chunk]
  const int tid = threadIdx.x;
  const int m0 = blockIdx.x * BM;
  const int ky = blockIdx.y;
  const int kbase = ky * K_PER_SPLIT;
  const int lane = tid & 63;
  const int wave = tid >> 6;
  const int quad = lane >> 4;
  const int l16 = lane & 15;
  const int b_first = m0 / V_DIM;
  const int d_first = kbase >> 6;         // k = d*64 + p; one chunk == one d

  if (tid < 40) lds_pool[tid] = 0.0f;

  floatx4 acc[10];                        // wave: rows [wave*16,+16), all 160 n
  #pragma unroll
  for (int nt = 0; nt < 10; ++nt) acc[nt] = (floatx4)(0.0f);

  // staging coords: A: idx=it*256+tid -> arow=idx>>4, u=idx&15 (float4 units;
  // 16-thread group = one row = one d). B: brow=idx>>3, g=idx&7 (short8 units).
  floatx4 pa[4];
  short8 pb[5];

#define ISSUE(c)                                                                \
  {                                                                             \
    const int kc = kbase + (c) * BK;                                            \
    _Pragma("unroll")                                                           \
    for (int it = 0; it < 4; ++it) {                                            \
      int idx = it * 256 + tid;                                                 \
      int arow = idx >> 4;                                                      \
      int u = idx & 15;                                                         \
      int m = m0 + arow;                                                        \
      pa[it] = (m < M_TOTAL)                                                    \
          ? *(const floatx4*)(x + (size_t)m * K_TOTAL + kc + u * 4)             \
          : (floatx4)(0.0f);                                                    \
    }                                                                           \
    _Pragma("unroll")                                                           \
    for (int it = 0; it < 5; ++it) {                                            \
      int idx = it * 256 + tid;                                                 \
      int brow = idx >> 3;                                                      \
      int g = idx & 7;                                                          \
      pb[it] = *(const short8*)(Wb + (size_t)brow * K_TOTAL + kc + g * 8);      \
    }                                                                           \
  }

#define CONVERT_WRITE(c)                                                        \
  {                                                                             \
    _Pragma("unroll")                                                           \
    for (int it = 0; it < 4; ++it) {                                            \
      int idx = it * 256 + tid;                                                 \
      int arow = idx >> 4;                                                      \
      int u = idx & 15;                                                         \
      int m = m0 + arow;                                                        \
      floatx4 v = pa[it];                                                       \
      /* pooling: 16-thread group = one (row, d); one LDS atomic per group */   \
      float s = (v[0] + v[1]) + (v[2] + v[3]);                                  \
      s += __shfl_down(s, 8, 16);                                               \
      s += __shfl_down(s, 4, 16);                                               \
      s += __shfl_down(s, 2, 16);                                               \
      s += __shfl_down(s, 1, 16);                                               \
      if ((tid & 15) == 0 && m < M_TOTAL) {                                     \
        int b_local = (m / V_DIM) - b_first;                                    \
        atomicAdd(&lds_pool[b_local * 8 + (c)], s);                             \
      }                                                                         \
      shortx4 sv;                                                               \
      sv[0] = (short)f2bf(v[0]); sv[1] = (short)f2bf(v[1]);                     \
      sv[2] = (short)f2bf(v[2]); sv[3] = (short)f2bf(v[3]);                     \
      *(shortx4*)&ldsA[arow * LDS_K + u * 4] = sv;                              \
    }                                                                           \
    _Pragma("unroll")                                                           \
    for (int it = 0; it < 5; ++it) {                                            \
      int idx = it * 256 + tid;                                                 \
      int brow = idx >> 3;                                                      \
      int g = idx & 7;                                                          \
      *(short8*)&ldsB[brow * LDS_K + g * 8] = pb[it];                           \
    }                                                                           \
  }

  ISSUE(0);
  __syncthreads();          // lds_pool zeros visible before first atomicAdd
  CONVERT_WRITE(0);

  for (int c = 0; c < CHUNKS; ++c) {
    __syncthreads();        // LDS tiles for chunk c ready
    if (c + 1 < CHUNKS) ISSUE(c + 1);     // next chunk's loads fly under MFMA
    #pragma unroll
    for (int ks = 0; ks < 2; ++ks) {
      const int ko = ks * 32 + quad * 8;
      short8 a = *(const short8*)&ldsA[(wave * 16 + l16) * LDS_K + ko];
      #pragma unroll
      for (int nt = 0; nt < 10; ++nt) {
        short8 b = *(const short8*)&ldsB[(nt * 16 + l16) * LDS_K + ko];
        acc[nt] = __builtin_amdgcn_mfma_f32_16x16x32_bf16(a, b, acc[nt], 0, 0, 0);
      }
    }
    __syncthreads();        // all LDS reads of chunk c done
    if (c + 1 < CHUNKS) CONVERT_WRITE(c + 1);
  }

  // partial-plane store (D layout: col=lane&15, row=quad*4+reg) — plain stores
  {
    const int mrow = m0 + wave * 16 + quad * 4;
    float* Pp = P + (size_t)ky * SMN + (size_t)mrow * N_TOTAL + l16;
    #pragma unroll
    for (int r = 0; r < 4; ++r)
      if (mrow + r < M_TOTAL)
        #pragma unroll
        for (int nt = 0; nt < 10; ++nt)
          Pp[(size_t)r * N_TOTAL + nt * 16] = acc[nt][r];
  }

  // pooled partials -> global (40 atomics/block)
  if (tid < 40) {
    int b = b_first + (tid >> 3);
    int d = d_first + (tid & 7);
    if (b < B_DIM)
      atomicAdd(&pooled[b * D_DIM + d], lds_pool[tid] * POOL_SCALE);
  }
}

// ---------------- router: MLP + softmax + top-2 ------------------------------
__global__ __launch_bounds__(256)
void router_kernel(const float* __restrict__ pooled, const float* __restrict__ W1,
                   const float* __restrict__ b1, const float* __restrict__ W2,
                   const float* __restrict__ b2, float* __restrict__ wfull,
                   float* __restrict__ probs_out) {
  __shared__ float sp[D_DIM];
  __shared__ float sh[H_DIM];
  __shared__ float slog[E_DIM];
  const int b = blockIdx.x;
  const int t = threadIdx.x;
  sp[t] = pooled[b * D_DIM + t];
  sp[t + 256] = pooled[b * D_DIM + t + 256];
  __syncthreads();
  float acc = b1[t];
  const float* w1r = W1 + (size_t)t * D_DIM;
  for (int d = 0; d < D_DIM; ++d) acc += sp[d] * w1r[d];
  sh[t] = fmaxf(acc, 0.0f);
  __syncthreads();
  if (t < E_DIM) {
    float a = b2[t];
    const float* w2r = W2 + t * H_DIM;
    for (int j = 0; j < H_DIM; ++j) a += sh[j] * w2r[j];
    slog[t] = a;
  }
  __syncthreads();
  if (t == 0) {
    float p[E_DIM];
    float mx = slog[0];
    for (int e = 1; e < E_DIM; ++e) mx = fmaxf(mx, slog[e]);
    float se = 0.0f;
    for (int e = 0; e < E_DIM; ++e) { p[e] = __expf(slog[e] - mx); se += p[e]; }
    float inv = 1.0f / se;
    for (int e = 0; e < E_DIM; ++e) { p[e] *= inv; probs_out[b * E_DIM + e] = p[e]; }
    // top-2, lowest index wins ties (strict > keeps earlier index)
    int i0 = 0;
    for (int e = 1; e < E_DIM; ++e) if (p[e] > p[i0]) i0 = e;
    int i1 = (i0 == 0) ? 1 : 0;
    for (int e = 0; e < E_DIM; ++e) if (e != i0 && p[e] > p[i1]) i1 = e;
    float s2 = p[i0] + p[i1];
    float invs = 1.0f / fmaxf(s2, 1e-6f);
    for (int e = 0; e < E_DIM; ++e) {
      float w = 0.0f;
      if (e == i0) w += p[i0] * invs;
      if (e == i1) w += p[i1] * invs;
      wfull[b * E_DIM + e] = w;
    }
  }
}

// ------- reduce partials over KSPLIT + combine: out = S_b + b_base + 2*Σ w·(S_l·B)
// float4 P loads (4x in-flight bytes), RC_ROWS=4 -> 168 blocks.
__global__ __launch_bounds__(256)
void reduce_combine_kernel(const float* __restrict__ P, const float* __restrict__ b_base,
                           const float* __restrict__ lora_B, const float* __restrict__ wfull,
                           float* __restrict__ out) {
  __shared__ float sS[RC_ROWS * N_TOTAL];   // 640 floats
  const int t = threadIdx.x;
  const int NF4 = RC_ROWS * N_TOTAL / 4;    // 160 float4 per block
  if (t < NF4) {
    const floatx4* P4 = (const floatx4*)P;
    size_t base = (size_t)blockIdx.x * NF4 + t;
    floatx4 a = (floatx4)(0.0f);
    #pragma unroll 8
    for (int k = 0; k < KSPLIT; ++k) a += P4[(size_t)k * (SMN / 4) + base];
    *(floatx4*)&sS[t * 4] = a;
  }
  __syncthreads();
  for (int i = t; i < RC_ROWS * OUT_DIM; i += 256) {
    int mr = i / OUT_DIM;
    int o = i - mr * OUT_DIM;
    int mm = blockIdx.x * RC_ROWS + mr;
    int b = mm / V_DIM;
    const float* srow = sS + mr * N_TOTAL;
    float res = srow[o] + b_base[o];
    float moe = 0.0f;
    #pragma unroll
    for (int e = 0; e < E_DIM; ++e) {
      float we = wfull[b * E_DIM + e];
      if (we != 0.0f) {
        const float* lb = lora_B + ((size_t)e * OUT_DIM + o) * R_DIM;
        float dd = 0.0f;
        #pragma unroll
        for (int r = 0; r < R_DIM; ++r) dd += srow[OUT_DIM + e * R_DIM + r] * lb[r];
        moe += we * dd;
      }
    }
    out[(size_t)mm * OUT_DIM + o] = res + SCALING * moe;
  }
}

extern "C" void kernel_launch(void* const* d_in, const int* in_sizes, int n_in,
                              void* d_out, int out_size, void* d_ws, size_t ws_size,
                              hipStream_t stream) {
  const float* x      = (const float*)d_in[0];
  const float* W_base = (const float*)d_in[1];
  const float* b_base = (const float*)d_in[2];
  const float* W1     = (const float*)d_in[3];
  const float* b1     = (const float*)d_in[4];
  const float* W2     = (const float*)d_in[5];
  const float* b2     = (const float*)d_in[6];
  const float* lora_A = (const float*)d_in[7];
  const float* lora_B = (const float*)d_in[8];
  float* out = (float*)d_out;

  // ws layout: pooled[16384 f] | wfull[256 f] | Wb[160*32768 bf16] | P[64*107520 f]
  float* ws     = (float*)d_ws;
  float* pooled = ws;
  float* wfull  = ws + 16384;
  short* Wb     = (short*)(wfull + 256);
  float* P      = (float*)(Wb + (size_t)N_TOTAL * K_TOTAL);

  convW_kernel<<<(N_TOTAL * K_TOTAL / 8 + 255) / 256, 256, 0, stream>>>(
      W_base, lora_A, Wb, pooled);
  gemm_kernel<<<dim3(11, KSPLIT), 256, 0, stream>>>(x, Wb, P, pooled);
  router_kernel<<<B_DIM, 256, 0, stream>>>(pooled, W1, b1, W2, b2, wfull,
                                           out + (size_t)M_TOTAL * OUT_DIM);
  reduce_combine_kernel<<<M_TOTAL / RC_ROWS, 256, 0, stream>>>(
      P, b_base, lora_B, wfull, out);
}

// Round 11
// 203.939 us; speedup vs baseline: 1.1717x; 1.0097x over previous
//
#include <hip/hip_runtime.h>

// Problem constants
#define B_DIM 32
#define V_DIM 21
#define D_DIM 512
#define P_DIM 64
#define M_TOTAL 672          // B*V
#define K_TOTAL 32768        // D*P
#define OUT_DIM 96
#define E_DIM 8
#define R_DIM 8
#define H_DIM 256
#define N_TOTAL 160          // OUT_DIM + E*R
#define SCALING 2.0f
#define POOL_SCALE (1.0f / (V_DIM * (float)P_DIM))

// GEMM tiling: coalesced LDS staging, small tiles for residency.
#define BM 64
#define BK 64
#define KSPLIT 64
#define K_PER_SPLIT (K_TOTAL / KSPLIT)   // 512
#define CHUNKS (K_PER_SPLIT / BK)        // 8
#define LDS_K (BK + 8)                   // 72 shorts/row: row stride 144B -> 4-bank rotate
#define LDS_RED_S 20                     // pooled-scratch row stride (floats): 80B, 16B-aligned
#define SMN (M_TOTAL * N_TOTAL)          // 107520 per partial plane
#define RC_ROWS 4                        // rows per reduce_combine block

typedef __attribute__((ext_vector_type(4))) float floatx4;
typedef __attribute__((ext_vector_type(8))) short short8;
typedef __attribute__((ext_vector_type(4))) short shortx4;  // 'short4' is a HIP builtin

__device__ __forceinline__ unsigned short f2bf(float f) {
  union { float f; unsigned int u; } v; v.f = f;
  unsigned int u = v.u + (0x7FFFu + ((v.u >> 16) & 1u));  // RNE
  return (unsigned short)(u >> 16);
}

// ------- convW: [W_base|lora_A] fp32 -> bf16 Wb[160][32768]; also zero pooled
__global__ __launch_bounds__(256)
void convW_kernel(const float* __restrict__ W_base, const float* __restrict__ lora_A,
                  short* __restrict__ Wb, float* __restrict__ pooled) {
  int gid = blockIdx.x * 256 + threadIdx.x;
  if (blockIdx.x < 64) pooled[gid] = 0.0f;   // 16384 floats zeroed (grid is 2560 blocks)
  size_t base = (size_t)gid * 8;
  int row = (int)(base >> 15);
  int k = (int)(base & 32767);
  const float* src = (row < OUT_DIM) ? (W_base + ((size_t)row << 15) + k)
                                     : (lora_A + ((size_t)(row - OUT_DIM) << 15) + k);
  floatx4 v0 = ((const floatx4*)src)[0];
  floatx4 v1 = ((const floatx4*)src)[1];
  short8 sv;
  sv[0] = (short)f2bf(v0[0]); sv[1] = (short)f2bf(v0[1]);
  sv[2] = (short)f2bf(v0[2]); sv[3] = (short)f2bf(v0[3]);
  sv[4] = (short)f2bf(v1[0]); sv[5] = (short)f2bf(v1[1]);
  sv[6] = (short)f2bf(v1[2]); sv[7] = (short)f2bf(v1[3]);
  *(short8*)(Wb + base) = sv;
}

// ------- gemm: P[ky][m][n] = x-chunk @ Wb^T; A,B staged via LDS (coalesced);
// plain-store partials. Pooling v2: per-thread partials -> linear lds_red
// writes (published by the existing top-of-loop barrier), row-summed by 64
// threads in the compute phase. Replaces the 4-deep dependent shfl tree
// (16 ds-class ops/thread/chunk -> 4 writes + amortized reads). 4 blocks/CU.
__global__ __launch_bounds__(256, 4)
void gemm_kernel(const float* __restrict__ x, const short* __restrict__ Wb,
                 float* __restrict__ P, float* __restrict__ pooled) {
  __shared__ short ldsA[BM * LDS_K];      //  9,216 B
  __shared__ short ldsB[N_TOTAL * LDS_K]; // 23,040 B
  __shared__ float lds_pool[5 * 8];       // [b_local][d_local = chunk]
  __shared__ __attribute__((aligned(16))) float lds_red[BM * LDS_RED_S]; // 5,120 B
  const int tid = threadIdx.x;
  const int m0 = blockIdx.x * BM;
  const int ky = blockIdx.y;
  const int kbase = ky * K_PER_SPLIT;
  const int lane = tid & 63;
  const int wave = tid >> 6;
  const int quad = lane >> 4;
  const int l16 = lane & 15;
  const int b_first = m0 / V_DIM;
  const int d_first = kbase >> 6;         // k = d*64 + p; one chunk == one d

  if (tid < 40) lds_pool[tid] = 0.0f;

  floatx4 acc[10];                        // wave: rows [wave*16,+16), all 160 n
  #pragma unroll
  for (int nt = 0; nt < 10; ++nt) acc[nt] = (floatx4)(0.0f);

  // staging coords: A: idx=it*256+tid -> arow=idx>>4, u=idx&15 (float4 units;
  // 16-thread group = one row = one d). B: brow=idx>>3, g=idx&7 (short8 units).
  floatx4 pa[4];
  short8 pb[5];

#define ISSUE(c)                                                                \
  {                                                                             \
    const int kc = kbase + (c) * BK;                                            \
    _Pragma("unroll")                                                           \
    for (int it = 0; it < 4; ++it) {                                            \
      int idx = it * 256 + tid;                                                 \
      int arow = idx >> 4;                                                      \
      int u = idx & 15;                                                         \
      int m = m0 + arow;                                                        \
      pa[it] = (m < M_TOTAL)                                                    \
          ? *(const floatx4*)(x + (size_t)m * K_TOTAL + kc + u * 4)             \
          : (floatx4)(0.0f);                                                    \
    }                                                                           \
    _Pragma("unroll")                                                           \
    for (int it = 0; it < 5; ++it) {                                            \
      int idx = it * 256 + tid;                                                 \
      int brow = idx >> 3;                                                      \
      int g = idx & 7;                                                          \
      pb[it] = *(const short8*)(Wb + (size_t)brow * K_TOTAL + kc + g * 8);      \
    }                                                                           \
  }

#define CONVERT_WRITE(c)                                                        \
  {                                                                             \
    _Pragma("unroll")                                                           \
    for (int it = 0; it < 4; ++it) {                                            \
      int idx = it * 256 + tid;                                                 \
      int arow = idx >> 4;                                                      \
      int u = idx & 15;                                                         \
      floatx4 v = pa[it];                                                       \
      /* pooling partial: one scalar per (row, u-slot); linear, conflict-free */\
      lds_red[arow * LDS_RED_S + u] = (v[0] + v[1]) + (v[2] + v[3]);            \
      shortx4 sv;                                                               \
      sv[0] = (short)f2bf(v[0]); sv[1] = (short)f2bf(v[1]);                     \
      sv[2] = (short)f2bf(v[2]); sv[3] = (short)f2bf(v[3]);                     \
      *(shortx4*)&ldsA[arow * LDS_K + u * 4] = sv;                              \
    }                                                                           \
    _Pragma("unroll")                                                           \
    for (int it = 0; it < 5; ++it) {                                            \
      int idx = it * 256 + tid;                                                 \
      int brow = idx >> 3;                                                      \
      int g = idx & 7;                                                          \
      *(short8*)&ldsB[brow * LDS_K + g * 8] = pb[it];                           \
    }                                                                           \
  }

  ISSUE(0);
  __syncthreads();          // lds_pool zeros visible before first atomicAdd
  CONVERT_WRITE(0);

  for (int c = 0; c < CHUNKS; ++c) {
    __syncthreads();        // LDS tiles + lds_red for chunk c ready
    if (c + 1 < CHUNKS) ISSUE(c + 1);     // next chunk's loads fly under MFMA
    #pragma unroll
    for (int ks = 0; ks < 2; ++ks) {
      const int ko = ks * 32 + quad * 8;
      short8 a = *(const short8*)&ldsA[(wave * 16 + l16) * LDS_K + ko];
      #pragma unroll
      for (int nt = 0; nt < 10; ++nt) {
        short8 b = *(const short8*)&ldsB[(nt * 16 + l16) * LDS_K + ko];
        acc[nt] = __builtin_amdgcn_mfma_f32_16x16x32_bf16(a, b, acc[nt], 0, 0, 0);
      }
    }
    // row-sum of lds_red (chunk c = d_first + c): 64 threads, 16 per wave.
    // Reads complete before the bottom barrier; lds_red overwritten only
    // after it (CONVERT_WRITE(c+1)).
    if (quad == 0) {
      int r = wave * 16 + l16;
      const floatx4* rr = (const floatx4*)&lds_red[r * LDS_RED_S];
      floatx4 t0 = rr[0], t1 = rr[1], t2 = rr[2], t3 = rr[3];
      floatx4 tt = (t0 + t1) + (t2 + t3);
      float s = (tt[0] + tt[1]) + (tt[2] + tt[3]);
      int m = m0 + r;
      if (m < M_TOTAL)
        atomicAdd(&lds_pool[(m / V_DIM - b_first) * 8 + c], s);
    }
    __syncthreads();        // all LDS reads of chunk c done
    if (c + 1 < CHUNKS) CONVERT_WRITE(c + 1);
  }

  // partial-plane store (D layout: col=lane&15, row=quad*4+reg) — plain stores
  {
    const int mrow = m0 + wave * 16 + quad * 4;
    float* Pp = P + (size_t)ky * SMN + (size_t)mrow * N_TOTAL + l16;
    #pragma unroll
    for (int r = 0; r < 4; ++r)
      if (mrow + r < M_TOTAL)
        #pragma unroll
        for (int nt = 0; nt < 10; ++nt)
          Pp[(size_t)r * N_TOTAL + nt * 16] = acc[nt][r];
  }

  // pooled partials -> global (40 atomics/block); ordered by the loop's final
  // bottom barrier.
  if (tid < 40) {
    int b = b_first + (tid >> 3);
    int d = d_first + (tid & 7);
    if (b < B_DIM)
      atomicAdd(&pooled[b * D_DIM + d], lds_pool[tid] * POOL_SCALE);
  }
}

// ---------------- router: MLP + softmax + top-2 ------------------------------
__global__ __launch_bounds__(256)
void router_kernel(const float* __restrict__ pooled, const float* __restrict__ W1,
                   const float* __restrict__ b1, const float* __restrict__ W2,
                   const float* __restrict__ b2, float* __restrict__ wfull,
                   float* __restrict__ probs_out) {
  __shared__ float sp[D_DIM];
  __shared__ float sh[H_DIM];
  __shared__ float slog[E_DIM];
  const int b = blockIdx.x;
  const int t = threadIdx.x;
  sp[t] = pooled[b * D_DIM + t];
  sp[t + 256] = pooled[b * D_DIM + t + 256];
  __syncthreads();
  float acc = b1[t];
  const float* w1r = W1 + (size_t)t * D_DIM;
  for (int d = 0; d < D_DIM; ++d) acc += sp[d] * w1r[d];
  sh[t] = fmaxf(acc, 0.0f);
  __syncthreads();
  if (t < E_DIM) {
    float a = b2[t];
    const float* w2r = W2 + t * H_DIM;
    for (int j = 0; j < H_DIM; ++j) a += sh[j] * w2r[j];
    slog[t] = a;
  }
  __syncthreads();
  if (t == 0) {
    float p[E_DIM];
    float mx = slog[0];
    for (int e = 1; e < E_DIM; ++e) mx = fmaxf(mx, slog[e]);
    float se = 0.0f;
    for (int e = 0; e < E_DIM; ++e) { p[e] = __expf(slog[e] - mx); se += p[e]; }
    float inv = 1.0f / se;
    for (int e = 0; e < E_DIM; ++e) { p[e] *= inv; probs_out[b * E_DIM + e] = p[e]; }
    // top-2, lowest index wins ties (strict > keeps earlier index)
    int i0 = 0;
    for (int e = 1; e < E_DIM; ++e) if (p[e] > p[i0]) i0 = e;
    int i1 = (i0 == 0) ? 1 : 0;
    for (int e = 0; e < E_DIM; ++e) if (e != i0 && p[e] > p[i1]) i1 = e;
    float s2 = p[i0] + p[i1];
    float invs = 1.0f / fmaxf(s2, 1e-6f);
    for (int e = 0; e < E_DIM; ++e) {
      float w = 0.0f;
      if (e == i0) w += p[i0] * invs;
      if (e == i1) w += p[i1] * invs;
      wfull[b * E_DIM + e] = w;
    }
  }
}

// ------- reduce partials over KSPLIT + combine: out = S_b + b_base + 2*Σ w·(S_l·B)
// float4 P loads (4x in-flight bytes), RC_ROWS=4 -> 168 blocks.
__global__ __launch_bounds__(256)
void reduce_combine_kernel(const float* __restrict__ P, const float* __restrict__ b_base,
                           const float* __restrict__ lora_B, const float* __restrict__ wfull,
                           float* __restrict__ out) {
  __shared__ float sS[RC_ROWS * N_TOTAL];   // 640 floats
  const int t = threadIdx.x;
  const int NF4 = RC_ROWS * N_TOTAL / 4;    // 160 float4 per block
  if (t < NF4) {
    const floatx4* P4 = (const floatx4*)P;
    size_t base = (size_t)blockIdx.x * NF4 + t;
    floatx4 a = (floatx4)(0.0f);
    #pragma unroll 8
    for (int k = 0; k < KSPLIT; ++k) a += P4[(size_t)k * (SMN / 4) + base];
    *(floatx4*)&sS[t * 4] = a;
  }
  __syncthreads();
  for (int i = t; i < RC_ROWS * OUT_DIM; i += 256) {
    int mr = i / OUT_DIM;
    int o = i - mr * OUT_DIM;
    int mm = blockIdx.x * RC_ROWS + mr;
    int b = mm / V_DIM;
    const float* srow = sS + mr * N_TOTAL;
    float res = srow[o] + b_base[o];
    float moe = 0.0f;
    #pragma unroll
    for (int e = 0; e < E_DIM; ++e) {
      float we = wfull[b * E_DIM + e];
      if (we != 0.0f) {
        const float* lb = lora_B + ((size_t)e * OUT_DIM + o) * R_DIM;
        float dd = 0.0f;
        #pragma unroll
        for (int r = 0; r < R_DIM; ++r) dd += srow[OUT_DIM + e * R_DIM + r] * lb[r];
        moe += we * dd;
      }
    }
    out[(size_t)mm * OUT_DIM + o] = res + SCALING * moe;
  }
}

extern "C" void kernel_launch(void* const* d_in, const int* in_sizes, int n_in,
                              void* d_out, int out_size, void* d_ws, size_t ws_size,
                              hipStream_t stream) {
  const float* x      = (const float*)d_in[0];
  const float* W_base = (const float*)d_in[1];
  const float* b_base = (const float*)d_in[2];
  const float* W1     = (const float*)d_in[3];
  const float* b1     = (const float*)d_in[4];
  const float* W2     = (const float*)d_in[5];
  const float* b2     = (const float*)d_in[6];
  const float* lora_A = (const float*)d_in[7];
  const float* lora_B = (const float*)d_in[8];
  float* out = (float*)d_out;

  // ws layout: pooled[16384 f] | wfull[256 f] | Wb[160*32768 bf16] | P[64*107520 f]
  float* ws     = (float*)d_ws;
  float* pooled = ws;
  float* wfull  = ws + 16384;
  short* Wb     = (short*)(wfull + 256);
  float* P      = (float*)(Wb + (size_t)N_TOTAL * K_TOTAL);

  convW_kernel<<<(N_TOTAL * K_TOTAL / 8 + 255) / 256, 256, 0, stream>>>(
      W_base, lora_A, Wb, pooled);
  gemm_kernel<<<dim3(11, KSPLIT), 256, 0, stream>>>(x, Wb, P, pooled);
  router_kernel<<<B_DIM, 256, 0, stream>>>(pooled, W1, b1, W2, b2, wfull,
                                           out + (size_t)M_TOTAL * OUT_DIM);
  reduce_combine_kernel<<<M_TOTAL / RC_ROWS, 256, 0, stream>>>(
      P, b_base, lora_B, wfull, out);
}